// Round 7
// baseline (277.989 us; speedup 1.0000x reference)
//
#include <hip/hip_runtime.h>
#include <hip/hip_bf16.h>
#include <stdint.h>

// B=2, L=S=2048, D_MODEL=1024, H=16, E=64. Inputs/outputs fp32; intermediates bf16.
#define BATCH 2
#define SEQ   2048
#define DM    1024
#define NH    16
#define EH    64
#define MROWS (BATCH*SEQ)   // 4096

typedef __attribute__((ext_vector_type(8))) short  short8;   // MFMA A/B frag (8 bf16)
typedef __attribute__((ext_vector_type(4))) float  floatx4;  // MFMA C/D frag
typedef __attribute__((ext_vector_type(8))) unsigned short ushort8v;
typedef __attribute__((ext_vector_type(4))) unsigned short ushort4v;

// Half-up rounding (2 VALU): differs from RNE only on exact 0x8000 ties (p~2^-16).
__device__ __forceinline__ unsigned short f2bf(float f) {
    return (unsigned short)((__float_as_uint(f) + 0x8000u) >> 16);
}

__device__ __forceinline__ void gload_lds16(const void* g, void* l) {
    // async global->LDS, 16B/lane; LDS dest = wave-uniform base + lane*16
    __builtin_amdgcn_global_load_lds(
        (const __attribute__((address_space(1))) unsigned int*)g,
        (__attribute__((address_space(3))) unsigned int*)l, 16, 0, 0);
}

// ---------------------------------------------------------------------------
// Transpose+convert: W [K][N] fp32 -> WT [N][K] bf16. 32x32 LDS tiles.
// ---------------------------------------------------------------------------
__global__ __launch_bounds__(256)
void transpose_w(const float* __restrict__ W0, const float* __restrict__ W1,
                 const float* __restrict__ W2, const float* __restrict__ W3,
                 unsigned short* __restrict__ T0, unsigned short* __restrict__ T1,
                 unsigned short* __restrict__ T2, unsigned short* __restrict__ T3,
                 int zbase)
{
    int z = zbase + blockIdx.z;
    const float* W = (z == 0) ? W0 : (z == 1) ? W1 : (z == 2) ? W2 : W3;
    unsigned short* T = (z == 0) ? T0 : (z == 1) ? T1 : (z == 2) ? T2 : T3;
    __shared__ float t[32][33];
    const int tid = threadIdx.x;
    const int k0 = blockIdx.y * 32, n0 = blockIdx.x * 32;
    {
        int r = tid >> 3, c4 = (tid & 7) * 4;
        float4 u = *(const float4*)&W[(size_t)(k0 + r) * DM + n0 + c4];
        t[r][c4 + 0] = u.x; t[r][c4 + 1] = u.y; t[r][c4 + 2] = u.z; t[r][c4 + 3] = u.w;
    }
    __syncthreads();
    {
        int n = tid >> 3, k4 = (tid & 7) * 4;
        ushort4v o;
        o[0] = f2bf(t[k4 + 0][n]); o[1] = f2bf(t[k4 + 1][n]);
        o[2] = f2bf(t[k4 + 2][n]); o[3] = f2bf(t[k4 + 3][n]);
        *(ushort4v*)&T[(size_t)(n0 + n) * DM + k0 + k4] = o;
    }
}

// ---------------------------------------------------------------------------
// MFMA GEMM: tile 128 x (NT*16), BK=32, 256 thr / 4 waves.
// C = A @ W^T + bias; W is [N][K] bf16 (async-staged). Wave w: rows w*32..+31.
// AMODE: 0 = A fp32 (convert in staging), 1 = A bf16 (global_load_lds).
// outmode: 0 fp32 row-major, 1 bf16 head-major [B,H,S,E].
// ---------------------------------------------------------------------------
struct GemmArgs {
    const void* A[3];
    const unsigned short* W[3];
    const float* bias[3];
    void* C[3];
    int   outmode[3];
    float oscale[3];
};

template<int AMODE, int NT>
__global__ __launch_bounds__(256)
void gemm_mfma(GemmArgs ga)
{
    constexpr int BN = NT * 16;
    const int z = blockIdx.z;
    const void* Ag = ga.A[z];
    const unsigned short* Wt = ga.W[z];
    void* Cg = ga.C[z];

    __shared__ unsigned short As[128 * 32];  // [128][32], 64B rows (m97 layout)
    __shared__ unsigned short Bs[BN * 32];   // [BN][32],  rows = n

    const int tid = threadIdx.x;
    const int lane = tid & 63, w = tid >> 6;
    const int lane15 = lane & 15, quad = lane >> 4;
    const int row0 = blockIdx.y * 128, col0 = blockIdx.x * BN;

    floatx4 acc[2][NT] = {};

    for (int kt = 0; kt < DM; kt += 32) {
        __syncthreads();
        if (AMODE == 1) {
            const unsigned short* A = (const unsigned short*)Ag;
#pragma unroll
            for (int rr = 0; rr < 2; ++rr) {     // A: 512 chunks of 16B
                int c = rr * 256 + w * 64 + lane;
                int row = c >> 2, kel = (c & 3) * 8;
                gload_lds16(&A[(size_t)(row0 + row) * DM + kt + kel],
                            (char*)As + (size_t)(rr * 256 + w * 64) * 16);
            }
        } else {
            const float* A = (const float*)Ag;
#pragma unroll
            for (int rr = 0; rr < 2; ++rr) {
                int c = rr * 256 + tid;
                int row = c >> 2, kel = (c & 3) * 8;
                const float* p = &A[(size_t)(row0 + row) * DM + kt + kel];
                float4 u0 = *(const float4*)p;
                float4 u1 = *(const float4*)(p + 4);
                ushort8v o8;
                o8[0] = f2bf(u0.x); o8[1] = f2bf(u0.y); o8[2] = f2bf(u0.z); o8[3] = f2bf(u0.w);
                o8[4] = f2bf(u1.x); o8[5] = f2bf(u1.y); o8[6] = f2bf(u1.z); o8[7] = f2bf(u1.w);
                *(ushort8v*)&As[(size_t)c * 8] = o8;
            }
        }
        {   // B: BN*4 chunks of 16B via global_load_lds
#pragma unroll
            for (int rr = 0; rr < BN / 64; ++rr) {
                int c = rr * 256 + w * 64 + lane;
                int row = c >> 2, kel = (c & 3) * 8;
                gload_lds16(&Wt[(size_t)(col0 + row) * DM + kt + kel],
                            (char*)Bs + (size_t)(rr * 256 + w * 64) * 16);
            }
        }
        __syncthreads();

        short8 af[2], bf[NT];
#pragma unroll
        for (int i = 0; i < 2; ++i)
            af[i] = *(const short8*)&As[(w * 32 + i * 16 + lane15) * 32 + quad * 8];
#pragma unroll
        for (int j = 0; j < NT; ++j)
            bf[j] = *(const short8*)&Bs[(j * 16 + lane15) * 32 + quad * 8];
#pragma unroll
        for (int i = 0; i < 2; ++i)
#pragma unroll
            for (int j = 0; j < NT; ++j)
                acc[i][j] = __builtin_amdgcn_mfma_f32_16x16x32_bf16(af[i], bf[j], acc[i][j], 0, 0, 0);
    }

    const float* bias = ga.bias[z];
    const int om = ga.outmode[z];
    const float os = ga.oscale[z];
#pragma unroll
    for (int i = 0; i < 2; ++i) {
#pragma unroll
        for (int j = 0; j < NT; ++j) {
#pragma unroll
            for (int r = 0; r < 4; ++r) {
                int row = row0 + w * 32 + i * 16 + quad * 4 + r;
                int col = col0 + j * 16 + lane15;
                float v = (acc[i][j][r] + bias[col]) * os;
                if (om == 0) {
                    ((float*)Cg)[(size_t)row * DM + col] = v;
                } else {
                    int b = row >> 11, l = row & (SEQ - 1);
                    int h = col >> 6, e = col & (EH - 1);
                    size_t o = ((size_t)(b * NH + h) * SEQ + l) * EH + e;
                    ((unsigned short*)Cg)[o] = f2bf(v);
                }
            }
        }
    }
}

// ---------------------------------------------------------------------------
// V projection computed TRANSPOSED: C^T[e_gl][l_gl] = Wv^T @ values^T.
// A operand = WvT[e_gl][k] (bf16, async-staged); B operand = values[l_gl][k]
// (fp32 rows, convert-in-staging). Epilogue writes Vt[B,H,E,S] with lane15
// varying l -> CONTIGUOUS stores (fixes the 4KB-stride b16 scatter of om=2).
// Bias is indexed by ROW (e_gl). Tile 128x128, BK=32.
// ---------------------------------------------------------------------------
__global__ __launch_bounds__(256)
void gemm_vT(const unsigned short* __restrict__ WvT,
             const float* __restrict__ vals,
             const float* __restrict__ bv,
             unsigned short* __restrict__ Vt)
{
    __shared__ unsigned short As[128 * 32];  // WvT rows (e_gl)
    __shared__ unsigned short Bs[128 * 32];  // values rows (l_gl), converted

    const int tid = threadIdx.x;
    const int lane = tid & 63, w = tid >> 6;
    const int lane15 = lane & 15, quad = lane >> 4;
    const int row0 = blockIdx.y * 128;       // e_gl
    const int col0 = blockIdx.x * 128;       // l_gl (0..4095)

    floatx4 acc[2][8] = {};

    for (int kt = 0; kt < DM; kt += 32) {
        __syncthreads();
#pragma unroll
        for (int rr = 0; rr < 2; ++rr) {     // A: WvT bf16 async
            int c = rr * 256 + w * 64 + lane;
            int row = c >> 2, kel = (c & 3) * 8;
            gload_lds16(&WvT[(size_t)(row0 + row) * DM + kt + kel],
                        (char*)As + (size_t)(rr * 256 + w * 64) * 16);
        }
#pragma unroll
        for (int rr = 0; rr < 2; ++rr) {     // B: values fp32 -> bf16
            int c = rr * 256 + tid;
            int row = c >> 2, kel = (c & 3) * 8;
            const float* p = &vals[(size_t)(col0 + row) * DM + kt + kel];
            float4 u0 = *(const float4*)p;
            float4 u1 = *(const float4*)(p + 4);
            ushort8v o8;
            o8[0] = f2bf(u0.x); o8[1] = f2bf(u0.y); o8[2] = f2bf(u0.z); o8[3] = f2bf(u0.w);
            o8[4] = f2bf(u1.x); o8[5] = f2bf(u1.y); o8[6] = f2bf(u1.z); o8[7] = f2bf(u1.w);
            *(ushort8v*)&Bs[(size_t)c * 8] = o8;
        }
        __syncthreads();

        short8 af[2], bf[8];
#pragma unroll
        for (int i = 0; i < 2; ++i)
            af[i] = *(const short8*)&As[(w * 32 + i * 16 + lane15) * 32 + quad * 8];
#pragma unroll
        for (int j = 0; j < 8; ++j)
            bf[j] = *(const short8*)&Bs[(j * 16 + lane15) * 32 + quad * 8];
#pragma unroll
        for (int i = 0; i < 2; ++i)
#pragma unroll
            for (int j = 0; j < 8; ++j)
                acc[i][j] = __builtin_amdgcn_mfma_f32_16x16x32_bf16(af[i], bf[j], acc[i][j], 0, 0, 0);
    }

    // epilogue: row = e_gl (bias by row), col = l_gl; Vt[((b*NH+h)*EH+e)*SEQ + l]
#pragma unroll
    for (int i = 0; i < 2; ++i) {
#pragma unroll
        for (int j = 0; j < 8; ++j) {
#pragma unroll
            for (int r = 0; r < 4; ++r) {
                int row = row0 + w * 32 + i * 16 + quad * 4 + r;   // e_gl
                int col = col0 + j * 16 + lane15;                  // l_gl
                float v = acc[i][j][r] + bv[row];
                int h = row >> 6, e = row & (EH - 1);
                int b = col >> 11, l = col & (SEQ - 1);
                Vt[((size_t)(b * NH + h) * EH + e) * SEQ + l] = f2bf(v);
            }
        }
    }
}

// ---------------------------------------------------------------------------
// MFMA flash attention (round-6 core, unchanged). Block = 128 q, 4 waves,
// m=32 q/wave. S^T = K @ Q^T; max-free softmax; l = P @ ones MFMA; exp2
// builtin; K/V async-staged XOR-swizzled double-buffered, 1 barrier/iter.
// Q pre-scaled by 0.125*log2(e). Qh,Kh:[B,H,S,E]; Vt:[B,H,E,S]; ctx:[4096][1024].
// ---------------------------------------------------------------------------
__device__ __forceinline__ void stage_kv(const unsigned short* __restrict__ Kp,
                                         const unsigned short* __restrict__ Vp,
                                         int st, unsigned short* ksb, unsigned short* vsb,
                                         int w, int lane)
{
#pragma unroll
    for (int rr = 0; rr < 2; ++rr) {
        int p = rr * 256 + w * 64 + lane;      // LDS chunk position
        int row = p >> 3;
        int gch = (p & 7) ^ (row & 7);         // swizzled source chunk
        gload_lds16(&Kp[(size_t)(st + row) * EH + gch * 8],
                    ksb + (size_t)(rr * 256 + w * 64) * 8);
        gload_lds16(&Vp[(size_t)row * SEQ + st + gch * 8],
                    vsb + (size_t)(rr * 256 + w * 64) * 8);
    }
}

__global__ __launch_bounds__(256)
void attn_mfma(const unsigned short* __restrict__ Qh,
               const unsigned short* __restrict__ Kh,
               const unsigned short* __restrict__ Vt,
               unsigned short* __restrict__ ctx)
{
    __shared__ unsigned short Ks[2][64 * 64];   // swizzled [s][e]
    __shared__ unsigned short Vs[2][64 * 64];   // swizzled [e][s]
    __shared__ unsigned short Ps[128][72];      // [q_local][s], padded pitch

    const int tid = threadIdx.x;
    const int lane = tid & 63, w = tid >> 6;
    const int lane15 = lane & 15, quad = lane >> 4;
    const int qt = blockIdx.x, h = blockIdx.y, b = blockIdx.z;
    const size_t bh = (size_t)(b * NH + h);
    const unsigned short* Kp = Kh + bh * SEQ * EH;
    const unsigned short* Vp = Vt + bh * EH * SEQ;

    short8 qf[2][2];
    {
        const unsigned short* Qp =
            Qh + (bh * SEQ + (size_t)qt * 128 + w * 32 + lane15) * EH;
#pragma unroll
        for (int ks = 0; ks < 2; ++ks) {
            qf[0][ks] = *(const short8*)(Qp + ks * 32 + quad * 8);
            qf[1][ks] = *(const short8*)(Qp + 16 * EH + ks * 32 + quad * 8);
        }
    }
    short8 ones;
#pragma unroll
    for (int i = 0; i < 8; ++i) ones[i] = (short)0x3F80;   // bf16 1.0

    floatx4 o[2][4] = {};
    floatx4 lacc[2] = {};

    stage_kv(Kp, Vp, 0, Ks[0], Vs[0], w, lane);
    __syncthreads();
    int cur = 0;

    for (int st = 0; st < SEQ; st += 64) {
        int nxt = cur ^ 1;
        if (st + 64 < SEQ)
            stage_kv(Kp, Vp, st + 64, Ks[nxt], Vs[nxt], w, lane);
        const unsigned short* ksb = Ks[cur];
        const unsigned short* vsb = Vs[cur];

        floatx4 sacc[4][2] = {};
#pragma unroll
        for (int ts = 0; ts < 4; ++ts) {
#pragma unroll
            for (int ks = 0; ks < 2; ++ks) {
                short8 kf = *(const short8*)&ksb[((ts * 16 + lane15) << 6) +
                                                 ((((ks << 2) + quad) ^ (lane15 & 7)) << 3)];
                sacc[ts][0] = __builtin_amdgcn_mfma_f32_16x16x32_bf16(kf, qf[0][ks], sacc[ts][0], 0, 0, 0);
                sacc[ts][1] = __builtin_amdgcn_mfma_f32_16x16x32_bf16(kf, qf[1][ks], sacc[ts][1], 0, 0, 0);
            }
        }

        // P = exp2(S'); pack 4 consecutive-s bf16 -> one ds_write_b64 per tile
#pragma unroll
        for (int ts = 0; ts < 4; ++ts)
#pragma unroll
            for (int nq = 0; nq < 2; ++nq) {
                unsigned int u0 = __float_as_uint(__builtin_amdgcn_exp2f(sacc[ts][nq][0])) + 0x8000u;
                unsigned int u1 = __float_as_uint(__builtin_amdgcn_exp2f(sacc[ts][nq][1])) + 0x8000u;
                unsigned int u2 = __float_as_uint(__builtin_amdgcn_exp2f(sacc[ts][nq][2])) + 0x8000u;
                unsigned int u3 = __float_as_uint(__builtin_amdgcn_exp2f(sacc[ts][nq][3])) + 0x8000u;
                uint2 pk;
                pk.x = (u0 >> 16) | (u1 & 0xFFFF0000u);
                pk.y = (u2 >> 16) | (u3 & 0xFFFF0000u);
                *(uint2*)&Ps[w * 32 + nq * 16 + lane15][ts * 16 + quad * 4] = pk;
            }

        // O += P @ V ; l += P @ 1   (Ps rows wave-local: no barrier needed)
#pragma unroll
        for (int ks = 0; ks < 2; ++ks) {
            short8 pf[2];
#pragma unroll
            for (int mt = 0; mt < 2; ++mt) {
                pf[mt] = *(const short8*)&Ps[w * 32 + mt * 16 + lane15][ks * 32 + quad * 8];
                lacc[mt] = __builtin_amdgcn_mfma_f32_16x16x32_bf16(pf[mt], ones, lacc[mt], 0, 0, 0);
            }
#pragma unroll
            for (int t2 = 0; t2 < 4; ++t2) {
                short8 vf = *(const short8*)&vsb[((t2 * 16 + lane15) << 6) +
                                                 ((((ks << 2) + quad) ^ (lane15 & 7)) << 3)];
                o[0][t2] = __builtin_amdgcn_mfma_f32_16x16x32_bf16(pf[0], vf, o[0][t2], 0, 0, 0);
                o[1][t2] = __builtin_amdgcn_mfma_f32_16x16x32_bf16(pf[1], vf, o[1][t2], 0, 0, 0);
            }
        }
        __syncthreads();
        cur = nxt;
    }

#pragma unroll
    for (int mt = 0; mt < 2; ++mt) {
        float inv[4];
#pragma unroll
        for (int r = 0; r < 4; ++r) inv[r] = 1.0f / lacc[mt][r];
#pragma unroll
        for (int t2 = 0; t2 < 4; ++t2)
#pragma unroll
            for (int r = 0; r < 4; ++r) {
                int q = qt * 128 + w * 32 + mt * 16 + quad * 4 + r;
                int col = h * EH + t2 * 16 + lane15;
                ctx[((size_t)(b * SEQ + q)) * DM + col] = f2bf(o[mt][t2][r] * inv[r]);
            }
    }
}

extern "C" void kernel_launch(void* const* d_in, const int* in_sizes, int n_in,
                              void* d_out, int out_size, void* d_ws, size_t ws_size,
                              hipStream_t stream)
{
    const float* queries = (const float*)d_in[0];
    const float* keys    = (const float*)d_in[1];
    const float* values  = (const float*)d_in[2];
    const float* Wq = (const float*)d_in[3];
    const float* bq = (const float*)d_in[4];
    const float* Wk = (const float*)d_in[5];
    const float* bk = (const float*)d_in[6];
    const float* Wv = (const float*)d_in[7];
    const float* bv = (const float*)d_in[8];
    const float* Wo = (const float*)d_in[9];
    const float* bo = (const float*)d_in[10];
    float* out = (float*)d_out;

    // Single 32 MB workspace layout (ushort elems):
    //   [0,4M)   Qh    (WoT overlays after attn)
    //   [4M,8M)  Kh
    //   [8M,12M) Vt
    //   [12M,16M) ctx  (WqT/WkT/WvT live here until attn overwrites)
    unsigned short* ws = (unsigned short*)d_ws;
    const size_t MAT = (size_t)MROWS * DM;   // 4M elems
    const size_t WSZ = (size_t)DM * DM;      // 1M elems
    unsigned short* Qhp = ws;
    unsigned short* Khp = ws + MAT;
    unsigned short* Vtp = ws + 2 * MAT;
    unsigned short* ctx = ws + 3 * MAT;
    unsigned short* WqT = ctx;               // dead once attn writes ctx
    unsigned short* WkT = ctx + WSZ;
    unsigned short* WvT = ctx + 2 * WSZ;
    unsigned short* WoT = ws;                // overlays Qh after attn

    // 1/sqrt(EH) * log2(e): exp2(S') == exp(S/8)
    const float qscale = 0.125f * 1.44269504088896f;

    // 1. weight transposes Wq/Wk/Wv
    transpose_w<<<dim3(DM / 32, DM / 32, 3), 256, 0, stream>>>(
        Wq, Wk, Wv, Wo, WqT, WkT, WvT, WoT, 0);

    // 2. Q/K projections (fp32 A convert-in-staging, bf16 W async)
    GemmArgs pa;
    pa.A[0] = queries; pa.A[1] = keys;  pa.A[2] = keys;
    pa.W[0] = WqT;     pa.W[1] = WkT;   pa.W[2] = WkT;
    pa.bias[0] = bq;   pa.bias[1] = bk; pa.bias[2] = bk;
    pa.C[0] = Qhp;     pa.C[1] = Khp;   pa.C[2] = Khp;
    pa.outmode[0] = 1; pa.outmode[1] = 1; pa.outmode[2] = 1;
    pa.oscale[0] = qscale; pa.oscale[1] = 1.f; pa.oscale[2] = 1.f;
    gemm_mfma<0, 8><<<dim3(8, 32, 2), 256, 0, stream>>>(pa);

    // 3. V projection, transposed-output form (contiguous Vt writes)
    gemm_vT<<<dim3(32, 8), 256, 0, stream>>>(WvT, values, bv, Vtp);

    // 4. attention -> ctx (clobbers WqT/WkT/WvT, dead)
    attn_mfma<<<dim3(SEQ / 128, NH, BATCH), 256, 0, stream>>>(Qhp, Khp, Vtp, ctx);

    // 5. Wo transpose into dead Qh region
    transpose_w<<<dim3(DM / 32, DM / 32, 1), 256, 0, stream>>>(
        Wq, Wk, Wv, Wo, WqT, WkT, WvT, WoT, 3);

    // 6. output projection (bf16 ctx async, fp32 out)
    GemmArgs oa;
    oa.A[0] = ctx; oa.W[0] = WoT; oa.bias[0] = bo; oa.C[0] = out;
    oa.outmode[0] = 0; oa.oscale[0] = 1.f;
    oa.A[1] = oa.A[0]; oa.W[1] = oa.W[0]; oa.bias[1] = oa.bias[0]; oa.C[1] = oa.C[0];
    oa.outmode[1] = 0; oa.oscale[1] = 1.f;
    oa.A[2] = oa.A[0]; oa.W[2] = oa.W[0]; oa.bias[2] = oa.bias[0]; oa.C[2] = oa.C[0];
    oa.outmode[2] = 0; oa.oscale[2] = 1.f;
    gemm_mfma<1, 4><<<dim3(16, 32, 1), 256, 0, stream>>>(oa);
}

// Round 8
// 245.518 us; speedup vs baseline: 1.1323x; 1.1323x over previous
//
#include <hip/hip_runtime.h>
#include <hip/hip_bf16.h>
#include <stdint.h>

// B=2, L=S=2048, D_MODEL=1024, H=16, E=64. Inputs/outputs fp32; intermediates bf16.
#define BATCH 2
#define SEQ   2048
#define DM    1024
#define NH    16
#define EH    64
#define MROWS (BATCH*SEQ)   // 4096

typedef __attribute__((ext_vector_type(8))) short  short8;   // MFMA A/B frag (8 bf16)
typedef __attribute__((ext_vector_type(4))) float  floatx4;  // MFMA C/D frag
typedef __attribute__((ext_vector_type(8))) unsigned short ushort8v;
typedef __attribute__((ext_vector_type(4))) unsigned short ushort4v;

// Half-up rounding (2 VALU): differs from RNE only on exact 0x8000 ties (p~2^-16).
__device__ __forceinline__ unsigned short f2bf(float f) {
    return (unsigned short)((__float_as_uint(f) + 0x8000u) >> 16);
}

__device__ __forceinline__ void gload_lds16(const void* g, void* l) {
    // async global->LDS, 16B/lane; LDS dest = wave-uniform base + lane*16
    __builtin_amdgcn_global_load_lds(
        (const __attribute__((address_space(1))) unsigned int*)g,
        (__attribute__((address_space(3))) unsigned int*)l, 16, 0, 0);
}

// ---------------------------------------------------------------------------
// Transpose+convert: W [K][N] fp32 -> WT [N][K] bf16. 32x32 LDS tiles.
// ---------------------------------------------------------------------------
__global__ __launch_bounds__(256)
void transpose_w(const float* __restrict__ W0, const float* __restrict__ W1,
                 const float* __restrict__ W2, const float* __restrict__ W3,
                 unsigned short* __restrict__ T0, unsigned short* __restrict__ T1,
                 unsigned short* __restrict__ T2, unsigned short* __restrict__ T3,
                 int zbase)
{
    int z = zbase + blockIdx.z;
    const float* W = (z == 0) ? W0 : (z == 1) ? W1 : (z == 2) ? W2 : W3;
    unsigned short* T = (z == 0) ? T0 : (z == 1) ? T1 : (z == 2) ? T2 : T3;
    __shared__ float t[32][33];
    const int tid = threadIdx.x;
    const int k0 = blockIdx.y * 32, n0 = blockIdx.x * 32;
    {
        int r = tid >> 3, c4 = (tid & 7) * 4;
        float4 u = *(const float4*)&W[(size_t)(k0 + r) * DM + n0 + c4];
        t[r][c4 + 0] = u.x; t[r][c4 + 1] = u.y; t[r][c4 + 2] = u.z; t[r][c4 + 3] = u.w;
    }
    __syncthreads();
    {
        int n = tid >> 3, k4 = (tid & 7) * 4;
        ushort4v o;
        o[0] = f2bf(t[k4 + 0][n]); o[1] = f2bf(t[k4 + 1][n]);
        o[2] = f2bf(t[k4 + 2][n]); o[3] = f2bf(t[k4 + 3][n]);
        *(ushort4v*)&T[(size_t)(n0 + n) * DM + k0 + k4] = o;
    }
}

// ---------------------------------------------------------------------------
// Fused Q/K/V projection, one dispatch, grid (8,32,3). Tile 128x128, BK=32.
// z=0: Qh = queries@WqT^T + bq (head-major, *qscale)     [B,H,S,E]
// z=1: Kh = keys   @WkT^T + bk (head-major)              [B,H,S,E]
// z=2: Vt = (WvT @ values^T) + bv  (transposed output)   [B,H,E,S]
// XCD swizzle: block linear id -> (row,col) such that the fp32 operand's
// tile is pinned to one XCD (linear%8 fixed per tile) -> HBM fetch once,
// L2 re-reads. (Round-7 counter: FETCH 133 MB vs 36 ideal from col-major
// XCD round-robin.)
// Both modes: one fp32 operand (VALU-convert staging) + one bf16 async operand.
// ---------------------------------------------------------------------------
struct ProjArgs {
    const float* act[3];            // queries, keys, values
    const unsigned short* wt[3];    // WqT, WkT, WvT
    const float* bias[3];
    unsigned short* C[3];           // Qh, Kh, Vt
    float oscale[3];
};

__global__ __launch_bounds__(256)
void proj_qkv(ProjArgs pa)
{
    const int z = blockIdx.z;
    const bool vt = (z == 2);
    const int linear = (int)(blockIdx.x + gridDim.x * blockIdx.y);  // 0..255
    int rb, cb;
    if (!vt) { rb = linear & 31; cb = linear >> 5; }   // pin activation row-tile
    else     { cb = linear & 31; rb = linear >> 5; }   // pin values tile
    const int row0 = rb * 128, col0 = cb * 128;

    const float* act = pa.act[z];
    const unsigned short* wt = pa.wt[z];

    __shared__ unsigned short As[128 * 32];  // [128][32], 64B rows
    __shared__ unsigned short Bs[128 * 32];

    const int tid = threadIdx.x;
    const int lane = tid & 63, w = tid >> 6;
    const int lane15 = lane & 15, quad = lane >> 4;

    floatx4 acc[2][8] = {};

    for (int kt = 0; kt < DM; kt += 32) {
        __syncthreads();
        if (!vt) {
            // As <- activation rows (fp32 convert), Bs <- weight rows (async)
#pragma unroll
            for (int rr = 0; rr < 2; ++rr) {
                int c = rr * 256 + tid;
                int row = c >> 2, kel = (c & 3) * 8;
                const float* p = &act[(size_t)(row0 + row) * DM + kt + kel];
                float4 u0 = *(const float4*)p;
                float4 u1 = *(const float4*)(p + 4);
                ushort8v o8;
                o8[0] = f2bf(u0.x); o8[1] = f2bf(u0.y); o8[2] = f2bf(u0.z); o8[3] = f2bf(u0.w);
                o8[4] = f2bf(u1.x); o8[5] = f2bf(u1.y); o8[6] = f2bf(u1.z); o8[7] = f2bf(u1.w);
                *(ushort8v*)&As[(size_t)c * 8] = o8;
            }
#pragma unroll
            for (int rr = 0; rr < 2; ++rr) {
                int c = rr * 256 + w * 64 + lane;
                int row = c >> 2, kel = (c & 3) * 8;
                gload_lds16(&wt[(size_t)(col0 + row) * DM + kt + kel],
                            (char*)Bs + (size_t)(rr * 256 + w * 64) * 16);
            }
        } else {
            // As <- WvT rows (async), Bs <- values rows (fp32 convert)
#pragma unroll
            for (int rr = 0; rr < 2; ++rr) {
                int c = rr * 256 + w * 64 + lane;
                int row = c >> 2, kel = (c & 3) * 8;
                gload_lds16(&wt[(size_t)(row0 + row) * DM + kt + kel],
                            (char*)As + (size_t)(rr * 256 + w * 64) * 16);
            }
#pragma unroll
            for (int rr = 0; rr < 2; ++rr) {
                int c = rr * 256 + tid;
                int row = c >> 2, kel = (c & 3) * 8;
                const float* p = &act[(size_t)(col0 + row) * DM + kt + kel];
                float4 u0 = *(const float4*)p;
                float4 u1 = *(const float4*)(p + 4);
                ushort8v o8;
                o8[0] = f2bf(u0.x); o8[1] = f2bf(u0.y); o8[2] = f2bf(u0.z); o8[3] = f2bf(u0.w);
                o8[4] = f2bf(u1.x); o8[5] = f2bf(u1.y); o8[6] = f2bf(u1.z); o8[7] = f2bf(u1.w);
                *(ushort8v*)&Bs[(size_t)c * 8] = o8;
            }
        }
        __syncthreads();

        short8 af[2], bf[8];
#pragma unroll
        for (int i = 0; i < 2; ++i)
            af[i] = *(const short8*)&As[(w * 32 + i * 16 + lane15) * 32 + quad * 8];
#pragma unroll
        for (int j = 0; j < 8; ++j)
            bf[j] = *(const short8*)&Bs[(j * 16 + lane15) * 32 + quad * 8];
#pragma unroll
        for (int i = 0; i < 2; ++i)
#pragma unroll
            for (int j = 0; j < 8; ++j)
                acc[i][j] = __builtin_amdgcn_mfma_f32_16x16x32_bf16(af[i], bf[j], acc[i][j], 0, 0, 0);
    }

    const float* bias = pa.bias[z];
    const float os = pa.oscale[z];
    unsigned short* C = pa.C[z];
#pragma unroll
    for (int i = 0; i < 2; ++i) {
#pragma unroll
        for (int j = 0; j < 8; ++j) {
#pragma unroll
            for (int r = 0; r < 4; ++r) {
                int row = row0 + w * 32 + i * 16 + quad * 4 + r;
                int col = col0 + j * 16 + lane15;
                if (!vt) {
                    float v = (acc[i][j][r] + bias[col]) * os;
                    int b = row >> 11, l = row & (SEQ - 1);
                    int h = col >> 6,  e = col & (EH - 1);
                    C[((size_t)(b * NH + h) * SEQ + l) * EH + e] = f2bf(v);
                } else {
                    float v = acc[i][j][r] + bias[row];       // bias by e-row
                    int h = row >> 6,  e = row & (EH - 1);
                    int b = col >> 11, l = col & (SEQ - 1);
                    C[((size_t)(b * NH + h) * EH + e) * SEQ + l] = f2bf(v);
                }
            }
        }
    }
}

// ---------------------------------------------------------------------------
// Output projection: out[4096][1024] fp32 = ctx(bf16) @ WoT^T + bo.
// Tile 128x64 (NT=4), BK=32, grid (16,32), both operands async bf16.
// Same XCD swizzle (pin ctx row-tile).
// ---------------------------------------------------------------------------
__global__ __launch_bounds__(256)
void gemm_out(const unsigned short* __restrict__ ctx,
              const unsigned short* __restrict__ WoT,
              const float* __restrict__ bo,
              float* __restrict__ out)
{
    const int linear = (int)(blockIdx.x + gridDim.x * blockIdx.y);  // 0..511
    const int rb = linear & 31, cb = linear >> 5;                   // cb 0..15
    const int row0 = rb * 128, col0 = cb * 64;

    __shared__ unsigned short As[128 * 32];
    __shared__ unsigned short Bs[64 * 32];

    const int tid = threadIdx.x;
    const int lane = tid & 63, w = tid >> 6;
    const int lane15 = lane & 15, quad = lane >> 4;

    floatx4 acc[2][4] = {};

    for (int kt = 0; kt < DM; kt += 32) {
        __syncthreads();
#pragma unroll
        for (int rr = 0; rr < 2; ++rr) {
            int c = rr * 256 + w * 64 + lane;
            int row = c >> 2, kel = (c & 3) * 8;
            gload_lds16(&ctx[(size_t)(row0 + row) * DM + kt + kel],
                        (char*)As + (size_t)(rr * 256 + w * 64) * 16);
        }
        {
            int c = w * 64 + lane;                 // 256 chunks
            int row = c >> 2, kel = (c & 3) * 8;
            gload_lds16(&WoT[(size_t)(col0 + row) * DM + kt + kel],
                        (char*)Bs + (size_t)(w * 64) * 16);
        }
        __syncthreads();

        short8 af[2], bf[4];
#pragma unroll
        for (int i = 0; i < 2; ++i)
            af[i] = *(const short8*)&As[(w * 32 + i * 16 + lane15) * 32 + quad * 8];
#pragma unroll
        for (int j = 0; j < 4; ++j)
            bf[j] = *(const short8*)&Bs[(j * 16 + lane15) * 32 + quad * 8];
#pragma unroll
        for (int i = 0; i < 2; ++i)
#pragma unroll
            for (int j = 0; j < 4; ++j)
                acc[i][j] = __builtin_amdgcn_mfma_f32_16x16x32_bf16(af[i], bf[j], acc[i][j], 0, 0, 0);
    }

#pragma unroll
    for (int i = 0; i < 2; ++i)
#pragma unroll
        for (int j = 0; j < 4; ++j)
#pragma unroll
            for (int r = 0; r < 4; ++r) {
                int row = row0 + w * 32 + i * 16 + quad * 4 + r;
                int col = col0 + j * 16 + lane15;
                out[(size_t)row * DM + col] = acc[i][j][r] + bo[col];
            }
}

// ---------------------------------------------------------------------------
// MFMA flash attention (round-6 core). Block = 128 q, 4 waves, m=32 q/wave.
// S^T = K @ Q^T; max-free softmax; l = P @ ones MFMA; exp2 builtin;
// K/V async-staged XOR-swizzled double-buffered, 1 barrier/iter.
// Q pre-scaled by 0.125*log2(e). Qh,Kh:[B,H,S,E]; Vt:[B,H,E,S]; ctx:[4096][1024].
// ---------------------------------------------------------------------------
__device__ __forceinline__ void stage_kv(const unsigned short* __restrict__ Kp,
                                         const unsigned short* __restrict__ Vp,
                                         int st, unsigned short* ksb, unsigned short* vsb,
                                         int w, int lane)
{
#pragma unroll
    for (int rr = 0; rr < 2; ++rr) {
        int p = rr * 256 + w * 64 + lane;      // LDS chunk position
        int row = p >> 3;
        int gch = (p & 7) ^ (row & 7);         // swizzled source chunk
        gload_lds16(&Kp[(size_t)(st + row) * EH + gch * 8],
                    ksb + (size_t)(rr * 256 + w * 64) * 8);
        gload_lds16(&Vp[(size_t)row * SEQ + st + gch * 8],
                    vsb + (size_t)(rr * 256 + w * 64) * 8);
    }
}

__global__ __launch_bounds__(256)
void attn_mfma(const unsigned short* __restrict__ Qh,
               const unsigned short* __restrict__ Kh,
               const unsigned short* __restrict__ Vt,
               unsigned short* __restrict__ ctx)
{
    __shared__ unsigned short Ks[2][64 * 64];   // swizzled [s][e]
    __shared__ unsigned short Vs[2][64 * 64];   // swizzled [e][s]
    __shared__ unsigned short Ps[128][72];      // [q_local][s], padded pitch

    const int tid = threadIdx.x;
    const int lane = tid & 63, w = tid >> 6;
    const int lane15 = lane & 15, quad = lane >> 4;
    const int qt = blockIdx.x, h = blockIdx.y, b = blockIdx.z;
    const size_t bh = (size_t)(b * NH + h);
    const unsigned short* Kp = Kh + bh * SEQ * EH;
    const unsigned short* Vp = Vt + bh * EH * SEQ;

    short8 qf[2][2];
    {
        const unsigned short* Qp =
            Qh + (bh * SEQ + (size_t)qt * 128 + w * 32 + lane15) * EH;
#pragma unroll
        for (int ks = 0; ks < 2; ++ks) {
            qf[0][ks] = *(const short8*)(Qp + ks * 32 + quad * 8);
            qf[1][ks] = *(const short8*)(Qp + 16 * EH + ks * 32 + quad * 8);
        }
    }
    short8 ones;
#pragma unroll
    for (int i = 0; i < 8; ++i) ones[i] = (short)0x3F80;   // bf16 1.0

    floatx4 o[2][4] = {};
    floatx4 lacc[2] = {};

    stage_kv(Kp, Vp, 0, Ks[0], Vs[0], w, lane);
    __syncthreads();
    int cur = 0;

    for (int st = 0; st < SEQ; st += 64) {
        int nxt = cur ^ 1;
        if (st + 64 < SEQ)
            stage_kv(Kp, Vp, st + 64, Ks[nxt], Vs[nxt], w, lane);
        const unsigned short* ksb = Ks[cur];
        const unsigned short* vsb = Vs[cur];

        floatx4 sacc[4][2] = {};
#pragma unroll
        for (int ts = 0; ts < 4; ++ts) {
#pragma unroll
            for (int ks = 0; ks < 2; ++ks) {
                short8 kf = *(const short8*)&ksb[((ts * 16 + lane15) << 6) +
                                                 ((((ks << 2) + quad) ^ (lane15 & 7)) << 3)];
                sacc[ts][0] = __builtin_amdgcn_mfma_f32_16x16x32_bf16(kf, qf[0][ks], sacc[ts][0], 0, 0, 0);
                sacc[ts][1] = __builtin_amdgcn_mfma_f32_16x16x32_bf16(kf, qf[1][ks], sacc[ts][1], 0, 0, 0);
            }
        }

        // P = exp2(S'); pack 4 consecutive-s bf16 -> one ds_write_b64 per tile
#pragma unroll
        for (int ts = 0; ts < 4; ++ts)
#pragma unroll
            for (int nq = 0; nq < 2; ++nq) {
                unsigned int u0 = __float_as_uint(__builtin_amdgcn_exp2f(sacc[ts][nq][0])) + 0x8000u;
                unsigned int u1 = __float_as_uint(__builtin_amdgcn_exp2f(sacc[ts][nq][1])) + 0x8000u;
                unsigned int u2 = __float_as_uint(__builtin_amdgcn_exp2f(sacc[ts][nq][2])) + 0x8000u;
                unsigned int u3 = __float_as_uint(__builtin_amdgcn_exp2f(sacc[ts][nq][3])) + 0x8000u;
                uint2 pk;
                pk.x = (u0 >> 16) | (u1 & 0xFFFF0000u);
                pk.y = (u2 >> 16) | (u3 & 0xFFFF0000u);
                *(uint2*)&Ps[w * 32 + nq * 16 + lane15][ts * 16 + quad * 4] = pk;
            }

        // O += P @ V ; l += P @ 1   (Ps rows wave-local: no barrier needed)
#pragma unroll
        for (int ks = 0; ks < 2; ++ks) {
            short8 pf[2];
#pragma unroll
            for (int mt = 0; mt < 2; ++mt) {
                pf[mt] = *(const short8*)&Ps[w * 32 + mt * 16 + lane15][ks * 32 + quad * 8];
                lacc[mt] = __builtin_amdgcn_mfma_f32_16x16x32_bf16(pf[mt], ones, lacc[mt], 0, 0, 0);
            }
#pragma unroll
            for (int t2 = 0; t2 < 4; ++t2) {
                short8 vf = *(const short8*)&vsb[((t2 * 16 + lane15) << 6) +
                                                 ((((ks << 2) + quad) ^ (lane15 & 7)) << 3)];
                o[0][t2] = __builtin_amdgcn_mfma_f32_16x16x32_bf16(pf[0], vf, o[0][t2], 0, 0, 0);
                o[1][t2] = __builtin_amdgcn_mfma_f32_16x16x32_bf16(pf[1], vf, o[1][t2], 0, 0, 0);
            }
        }
        __syncthreads();
        cur = nxt;
    }

#pragma unroll
    for (int mt = 0; mt < 2; ++mt) {
        float inv[4];
#pragma unroll
        for (int r = 0; r < 4; ++r) inv[r] = 1.0f / lacc[mt][r];
#pragma unroll
        for (int t2 = 0; t2 < 4; ++t2)
#pragma unroll
            for (int r = 0; r < 4; ++r) {
                int q = qt * 128 + w * 32 + mt * 16 + quad * 4 + r;
                int col = h * EH + t2 * 16 + lane15;
                ctx[((size_t)(b * SEQ + q)) * DM + col] = f2bf(o[mt][t2][r] * inv[r]);
            }
    }
}

extern "C" void kernel_launch(void* const* d_in, const int* in_sizes, int n_in,
                              void* d_out, int out_size, void* d_ws, size_t ws_size,
                              hipStream_t stream)
{
    const float* queries = (const float*)d_in[0];
    const float* keys    = (const float*)d_in[1];
    const float* values  = (const float*)d_in[2];
    const float* Wq = (const float*)d_in[3];
    const float* bq = (const float*)d_in[4];
    const float* Wk = (const float*)d_in[5];
    const float* bk = (const float*)d_in[6];
    const float* Wv = (const float*)d_in[7];
    const float* bv = (const float*)d_in[8];
    const float* Wo = (const float*)d_in[9];
    const float* bo = (const float*)d_in[10];
    float* out = (float*)d_out;

    // 32 MB workspace (ushort elems):
    //   [0,4M)   Qh    (WoT overlays after attn)
    //   [4M,8M)  Kh
    //   [8M,12M) Vt
    //   [12M,16M) ctx  (WqT/WkT/WvT live here until attn overwrites)
    unsigned short* ws = (unsigned short*)d_ws;
    const size_t MAT = (size_t)MROWS * DM;   // 4M elems
    const size_t WSZ = (size_t)DM * DM;      // 1M elems
    unsigned short* Qhp = ws;
    unsigned short* Khp = ws + MAT;
    unsigned short* Vtp = ws + 2 * MAT;
    unsigned short* ctx = ws + 3 * MAT;
    unsigned short* WqT = ctx;               // dead once attn writes ctx
    unsigned short* WkT = ctx + WSZ;
    unsigned short* WvT = ctx + 2 * WSZ;
    unsigned short* WoT = ws;                // overlays Qh after attn

    // 1/sqrt(EH) * log2(e): exp2(S') == exp(S/8)
    const float qscale = 0.125f * 1.44269504088896f;

    // 1. weight transposes Wq/Wk/Wv
    transpose_w<<<dim3(DM / 32, DM / 32, 3), 256, 0, stream>>>(
        Wq, Wk, Wv, Wo, WqT, WkT, WvT, WoT, 0);

    // 2. fused Q/K/V projections (XCD-pinned swizzle)
    ProjArgs pa;
    pa.act[0] = queries; pa.act[1] = keys; pa.act[2] = values;
    pa.wt[0] = WqT;      pa.wt[1] = WkT;   pa.wt[2] = WvT;
    pa.bias[0] = bq;     pa.bias[1] = bk;  pa.bias[2] = bv;
    pa.C[0] = Qhp;       pa.C[1] = Khp;    pa.C[2] = Vtp;
    pa.oscale[0] = qscale; pa.oscale[1] = 1.f; pa.oscale[2] = 1.f;
    proj_qkv<<<dim3(8, 32, 3), 256, 0, stream>>>(pa);

    // 3. attention -> ctx (clobbers WqT/WkT/WvT, dead)
    attn_mfma<<<dim3(SEQ / 128, NH, BATCH), 256, 0, stream>>>(Qhp, Khp, Vtp, ctx);

    // 4. Wo transpose into dead Qh region
    transpose_w<<<dim3(DM / 32, DM / 32, 1), 256, 0, stream>>>(
        Wq, Wk, Wv, Wo, WqT, WkT, WvT, WoT, 3);

    // 5. output projection (XCD-pinned swizzle)
    gemm_out<<<dim3(16, 32), 256, 0, stream>>>(ctx, WoT, bo, out);
}

// Round 9
// 233.483 us; speedup vs baseline: 1.1906x; 1.0515x over previous
//
#include <hip/hip_runtime.h>
#include <hip/hip_bf16.h>
#include <stdint.h>

// B=2, L=S=2048, D_MODEL=1024, H=16, E=64. Inputs/outputs fp32; intermediates bf16.
#define BATCH 2
#define SEQ   2048
#define DM    1024
#define NH    16
#define EH    64
#define MROWS (BATCH*SEQ)   // 4096

typedef __attribute__((ext_vector_type(8))) short  short8;   // MFMA A/B frag (8 bf16)
typedef __attribute__((ext_vector_type(4))) float  floatx4;  // MFMA C/D frag
typedef __attribute__((ext_vector_type(8))) unsigned short ushort8v;
typedef __attribute__((ext_vector_type(4))) unsigned short ushort4v;

// Half-up rounding (2 VALU): differs from RNE only on exact 0x8000 ties (p~2^-16).
__device__ __forceinline__ unsigned short f2bf(float f) {
    return (unsigned short)((__float_as_uint(f) + 0x8000u) >> 16);
}

__device__ __forceinline__ void gload_lds16(const void* g, void* l) {
    // async global->LDS, 16B/lane; LDS dest = wave-uniform base + lane*16
    __builtin_amdgcn_global_load_lds(
        (const __attribute__((address_space(1))) unsigned int*)g,
        (__attribute__((address_space(3))) unsigned int*)l, 16, 0, 0);
}

// ---------------------------------------------------------------------------
// Transpose+convert: W [K][N] fp32 -> WT [N][K] bf16. 32x32 LDS tiles.
// ---------------------------------------------------------------------------
__global__ __launch_bounds__(256)
void transpose_w(const float* __restrict__ W0, const float* __restrict__ W1,
                 const float* __restrict__ W2, const float* __restrict__ W3,
                 unsigned short* __restrict__ T0, unsigned short* __restrict__ T1,
                 unsigned short* __restrict__ T2, unsigned short* __restrict__ T3,
                 int zbase)
{
    int z = zbase + blockIdx.z;
    const float* W = (z == 0) ? W0 : (z == 1) ? W1 : (z == 2) ? W2 : W3;
    unsigned short* T = (z == 0) ? T0 : (z == 1) ? T1 : (z == 2) ? T2 : T3;
    __shared__ float t[32][33];
    const int tid = threadIdx.x;
    const int k0 = blockIdx.y * 32, n0 = blockIdx.x * 32;
    {
        int r = tid >> 3, c4 = (tid & 7) * 4;
        float4 u = *(const float4*)&W[(size_t)(k0 + r) * DM + n0 + c4];
        t[r][c4 + 0] = u.x; t[r][c4 + 1] = u.y; t[r][c4 + 2] = u.z; t[r][c4 + 3] = u.w;
    }
    __syncthreads();
    {
        int n = tid >> 3, k4 = (tid & 7) * 4;
        ushort4v o;
        o[0] = f2bf(t[k4 + 0][n]); o[1] = f2bf(t[k4 + 1][n]);
        o[2] = f2bf(t[k4 + 2][n]); o[3] = f2bf(t[k4 + 3][n]);
        *(ushort4v*)&T[(size_t)(n0 + n) * DM + k0 + k4] = o;
    }
}

// ---------------------------------------------------------------------------
// Fused Q/K/V projection, grid (8,32,3), tile 128x128, BK=32.
// z=0: Qh = queries@WqT^T + bq (head-major, *qscale)     [B,H,S,E]
// z=1: Kh = keys   @WkT^T + bk (head-major)              [B,H,S,E]
// z=2: Vt = (WvT @ values^T) + bv  (transposed output)   [B,H,E,S]
// XCD swizzle pins the fp32 activation tile to one XCD (r8: FETCH 133->49MB).
// NEW (r9): register-prefetch pipeline for the fp32 operand — loads for tile
// k+1 are issued AFTER the post-staging barrier so its vmcnt(0) doesn't drain
// them; they land during the MFMA phase. (r8 counters: MfmaUtil 12%,
// VALUBusy 15%, HBM 12% -> latency-bound serialized load->cvt->barrier chain.)
// ---------------------------------------------------------------------------
struct ProjArgs {
    const float* act[3];            // queries, keys, values
    const unsigned short* wt[3];    // WqT, WkT, WvT
    const float* bias[3];
    unsigned short* C[3];           // Qh, Kh, Vt
    float oscale[3];
};

__global__ __launch_bounds__(256)
void proj_qkv(ProjArgs pa)
{
    const int z = blockIdx.z;
    const bool vt = (z == 2);
    const int linear = (int)(blockIdx.x + gridDim.x * blockIdx.y);  // 0..255
    int rb, cb;
    if (!vt) { rb = linear & 31; cb = linear >> 5; }   // pin activation row-tile
    else     { cb = linear & 31; rb = linear >> 5; }   // pin values tile
    const int row0 = rb * 128, col0 = cb * 128;

    const float* act = pa.act[z];
    const unsigned short* wt = pa.wt[z];
    const int actBase = vt ? col0 : row0;   // act rows staged (fp32 -> cvt)
    const int wtBase  = vt ? row0 : col0;   // weight rows staged (async bf16)

    __shared__ unsigned short As[128 * 32];  // [128][32], 64B rows
    __shared__ unsigned short Bs[128 * 32];
    unsigned short* convDst  = vt ? Bs : As;
    unsigned short* asyncDst = vt ? As : Bs;

    const int tid = threadIdx.x;
    const int lane = tid & 63, w = tid >> 6;
    const int lane15 = lane & 15, quad = lane >> 4;

    floatx4 acc[2][8] = {};

    // per-thread fp32 prefetch regs: chunks c = rr*256+tid (row=c>>2, kel=(c&3)*8)
    float4 pre[4];
    {
        const float* p0 = &act[(size_t)(actBase + (tid >> 2)) * DM + ((tid & 3) * 8)];
        const float* p1 = &act[(size_t)(actBase + ((256 + tid) >> 2)) * DM + ((tid & 3) * 8)];
        pre[0] = *(const float4*)p0; pre[1] = *(const float4*)(p0 + 4);
        pre[2] = *(const float4*)p1; pre[3] = *(const float4*)(p1 + 4);
    }

    for (int kt = 0; kt < DM; kt += 32) {
        __syncthreads();                     // LDS consumers done; drains prefetch
        // cvt regs -> LDS
#pragma unroll
        for (int rr = 0; rr < 2; ++rr) {
            int c = rr * 256 + tid;
            ushort8v o8;
            float4 u0 = pre[rr * 2], u1 = pre[rr * 2 + 1];
            o8[0] = f2bf(u0.x); o8[1] = f2bf(u0.y); o8[2] = f2bf(u0.z); o8[3] = f2bf(u0.w);
            o8[4] = f2bf(u1.x); o8[5] = f2bf(u1.y); o8[6] = f2bf(u1.z); o8[7] = f2bf(u1.w);
            *(ushort8v*)&convDst[(size_t)c * 8] = o8;
        }
        // async bf16 weight staging
#pragma unroll
        for (int rr = 0; rr < 2; ++rr) {
            int c = rr * 256 + w * 64 + lane;
            int row = c >> 2, kel = (c & 3) * 8;
            gload_lds16(&wt[(size_t)(wtBase + row) * DM + kt + kel],
                        (char*)asyncDst + (size_t)(rr * 256 + w * 64) * 16);
        }
        __syncthreads();                     // drains async weight loads only

        // issue NEXT k-tile fp32 loads (land during MFMA below)
        if (kt + 32 < DM) {
            int kn = kt + 32;
            const float* p0 = &act[(size_t)(actBase + (tid >> 2)) * DM + kn + ((tid & 3) * 8)];
            const float* p1 = &act[(size_t)(actBase + ((256 + tid) >> 2)) * DM + kn + ((tid & 3) * 8)];
            pre[0] = *(const float4*)p0; pre[1] = *(const float4*)(p0 + 4);
            pre[2] = *(const float4*)p1; pre[3] = *(const float4*)(p1 + 4);
        }

        short8 af[2], bf[8];
#pragma unroll
        for (int i = 0; i < 2; ++i)
            af[i] = *(const short8*)&As[(w * 32 + i * 16 + lane15) * 32 + quad * 8];
#pragma unroll
        for (int j = 0; j < 8; ++j)
            bf[j] = *(const short8*)&Bs[(j * 16 + lane15) * 32 + quad * 8];
#pragma unroll
        for (int i = 0; i < 2; ++i)
#pragma unroll
            for (int j = 0; j < 8; ++j)
                acc[i][j] = __builtin_amdgcn_mfma_f32_16x16x32_bf16(af[i], bf[j], acc[i][j], 0, 0, 0);
    }

    const float* bias = pa.bias[z];
    const float os = pa.oscale[z];
    unsigned short* C = pa.C[z];
#pragma unroll
    for (int i = 0; i < 2; ++i) {
#pragma unroll
        for (int j = 0; j < 8; ++j) {
#pragma unroll
            for (int r = 0; r < 4; ++r) {
                int row = row0 + w * 32 + i * 16 + quad * 4 + r;
                int col = col0 + j * 16 + lane15;
                if (!vt) {
                    float v = (acc[i][j][r] + bias[col]) * os;
                    int b = row >> 11, l = row & (SEQ - 1);
                    int h = col >> 6,  e = col & (EH - 1);
                    C[((size_t)(b * NH + h) * SEQ + l) * EH + e] = f2bf(v);
                } else {
                    float v = acc[i][j][r] + bias[row];       // bias by e-row
                    int h = row >> 6,  e = row & (EH - 1);
                    int b = col >> 11, l = col & (SEQ - 1);
                    C[((size_t)(b * NH + h) * EH + e) * SEQ + l] = f2bf(v);
                }
            }
        }
    }
}

// ---------------------------------------------------------------------------
// Output projection: out[4096][1024] fp32 = ctx(bf16) @ WoT^T + bo.
// Tile 128x64 (NT=4), BK=32, grid (16,32), both operands async bf16.
// XCD swizzle pins the ctx row-tile.
// ---------------------------------------------------------------------------
__global__ __launch_bounds__(256)
void gemm_out(const unsigned short* __restrict__ ctx,
              const unsigned short* __restrict__ WoT,
              const float* __restrict__ bo,
              float* __restrict__ out)
{
    const int linear = (int)(blockIdx.x + gridDim.x * blockIdx.y);  // 0..511
    const int rb = linear & 31, cb = linear >> 5;                   // cb 0..15
    const int row0 = rb * 128, col0 = cb * 64;

    __shared__ unsigned short As[128 * 32];
    __shared__ unsigned short Bs[64 * 32];

    const int tid = threadIdx.x;
    const int lane = tid & 63, w = tid >> 6;
    const int lane15 = lane & 15, quad = lane >> 4;

    floatx4 acc[2][4] = {};

    for (int kt = 0; kt < DM; kt += 32) {
        __syncthreads();
#pragma unroll
        for (int rr = 0; rr < 2; ++rr) {
            int c = rr * 256 + w * 64 + lane;
            int row = c >> 2, kel = (c & 3) * 8;
            gload_lds16(&ctx[(size_t)(row0 + row) * DM + kt + kel],
                        (char*)As + (size_t)(rr * 256 + w * 64) * 16);
        }
        {
            int c = w * 64 + lane;                 // 256 chunks
            int row = c >> 2, kel = (c & 3) * 8;
            gload_lds16(&WoT[(size_t)(col0 + row) * DM + kt + kel],
                        (char*)Bs + (size_t)(w * 64) * 16);
        }
        __syncthreads();

        short8 af[2], bf[4];
#pragma unroll
        for (int i = 0; i < 2; ++i)
            af[i] = *(const short8*)&As[(w * 32 + i * 16 + lane15) * 32 + quad * 8];
#pragma unroll
        for (int j = 0; j < 4; ++j)
            bf[j] = *(const short8*)&Bs[(j * 16 + lane15) * 32 + quad * 8];
#pragma unroll
        for (int i = 0; i < 2; ++i)
#pragma unroll
            for (int j = 0; j < 4; ++j)
                acc[i][j] = __builtin_amdgcn_mfma_f32_16x16x32_bf16(af[i], bf[j], acc[i][j], 0, 0, 0);
    }

#pragma unroll
    for (int i = 0; i < 2; ++i)
#pragma unroll
        for (int j = 0; j < 4; ++j)
#pragma unroll
            for (int r = 0; r < 4; ++r) {
                int row = row0 + w * 32 + i * 16 + quad * 4 + r;
                int col = col0 + j * 16 + lane15;
                out[(size_t)row * DM + col] = acc[i][j][r] + bo[col];
            }
}

// ---------------------------------------------------------------------------
// MFMA flash attention (round-6 core) + (b,h)-pinned XCD swizzle (r9):
// all 16 q-tiles of one (b,h) share an XCD -> K/V L2 reuse (r8 FETCH 69.7MB
// vs ~25 ideal came from qt-major XCD assignment).
// S^T = K @ Q^T; max-free softmax; l = P @ ones MFMA; exp2 builtin;
// K/V async-staged XOR-swizzled double-buffered, 1 barrier/iter.
// Q pre-scaled by 0.125*log2(e). Qh,Kh:[B,H,S,E]; Vt:[B,H,E,S]; ctx:[4096][1024].
// ---------------------------------------------------------------------------
__device__ __forceinline__ void stage_kv(const unsigned short* __restrict__ Kp,
                                         const unsigned short* __restrict__ Vp,
                                         int st, unsigned short* ksb, unsigned short* vsb,
                                         int w, int lane)
{
#pragma unroll
    for (int rr = 0; rr < 2; ++rr) {
        int p = rr * 256 + w * 64 + lane;      // LDS chunk position
        int row = p >> 3;
        int gch = (p & 7) ^ (row & 7);         // swizzled source chunk
        gload_lds16(&Kp[(size_t)(st + row) * EH + gch * 8],
                    ksb + (size_t)(rr * 256 + w * 64) * 8);
        gload_lds16(&Vp[(size_t)row * SEQ + st + gch * 8],
                    vsb + (size_t)(rr * 256 + w * 64) * 8);
    }
}

__global__ __launch_bounds__(256)
void attn_mfma(const unsigned short* __restrict__ Qh,
               const unsigned short* __restrict__ Kh,
               const unsigned short* __restrict__ Vt,
               unsigned short* __restrict__ ctx)
{
    __shared__ unsigned short Ks[2][64 * 64];   // swizzled [s][e]
    __shared__ unsigned short Vs[2][64 * 64];   // swizzled [e][s]
    __shared__ unsigned short Ps[128][72];      // [q_local][s], padded pitch

    const int tid = threadIdx.x;
    const int lane = tid & 63, w = tid >> 6;
    const int lane15 = lane & 15, quad = lane >> 4;

    // (b,h)-pinned swizzle: linear%8 == bh%8 -> one XCD per 4 bh sets
    const int linear = (int)(blockIdx.x + 16 * (blockIdx.y + 16 * blockIdx.z));
    const int bhid = linear & 31;      // 0..31
    const int qt = linear >> 5;        // 0..15
    const int h = bhid & 15, b = bhid >> 4;

    const size_t bh = (size_t)(b * NH + h);
    const unsigned short* Kp = Kh + bh * SEQ * EH;
    const unsigned short* Vp = Vt + bh * EH * SEQ;

    short8 qf[2][2];
    {
        const unsigned short* Qp =
            Qh + (bh * SEQ + (size_t)qt * 128 + w * 32 + lane15) * EH;
#pragma unroll
        for (int ks = 0; ks < 2; ++ks) {
            qf[0][ks] = *(const short8*)(Qp + ks * 32 + quad * 8);
            qf[1][ks] = *(const short8*)(Qp + 16 * EH + ks * 32 + quad * 8);
        }
    }
    short8 ones;
#pragma unroll
    for (int i = 0; i < 8; ++i) ones[i] = (short)0x3F80;   // bf16 1.0

    floatx4 o[2][4] = {};
    floatx4 lacc[2] = {};

    stage_kv(Kp, Vp, 0, Ks[0], Vs[0], w, lane);
    __syncthreads();
    int cur = 0;

    for (int st = 0; st < SEQ; st += 64) {
        int nxt = cur ^ 1;
        if (st + 64 < SEQ)
            stage_kv(Kp, Vp, st + 64, Ks[nxt], Vs[nxt], w, lane);
        const unsigned short* ksb = Ks[cur];
        const unsigned short* vsb = Vs[cur];

        floatx4 sacc[4][2] = {};
#pragma unroll
        for (int ts = 0; ts < 4; ++ts) {
#pragma unroll
            for (int ks = 0; ks < 2; ++ks) {
                short8 kf = *(const short8*)&ksb[((ts * 16 + lane15) << 6) +
                                                 ((((ks << 2) + quad) ^ (lane15 & 7)) << 3)];
                sacc[ts][0] = __builtin_amdgcn_mfma_f32_16x16x32_bf16(kf, qf[0][ks], sacc[ts][0], 0, 0, 0);
                sacc[ts][1] = __builtin_amdgcn_mfma_f32_16x16x32_bf16(kf, qf[1][ks], sacc[ts][1], 0, 0, 0);
            }
        }

        // P = exp2(S'); pack 4 consecutive-s bf16 -> one ds_write_b64 per tile
#pragma unroll
        for (int ts = 0; ts < 4; ++ts)
#pragma unroll
            for (int nq = 0; nq < 2; ++nq) {
                unsigned int u0 = __float_as_uint(__builtin_amdgcn_exp2f(sacc[ts][nq][0])) + 0x8000u;
                unsigned int u1 = __float_as_uint(__builtin_amdgcn_exp2f(sacc[ts][nq][1])) + 0x8000u;
                unsigned int u2 = __float_as_uint(__builtin_amdgcn_exp2f(sacc[ts][nq][2])) + 0x8000u;
                unsigned int u3 = __float_as_uint(__builtin_amdgcn_exp2f(sacc[ts][nq][3])) + 0x8000u;
                uint2 pk;
                pk.x = (u0 >> 16) | (u1 & 0xFFFF0000u);
                pk.y = (u2 >> 16) | (u3 & 0xFFFF0000u);
                *(uint2*)&Ps[w * 32 + nq * 16 + lane15][ts * 16 + quad * 4] = pk;
            }

        // O += P @ V ; l += P @ 1   (Ps rows wave-local: no barrier needed)
#pragma unroll
        for (int ks = 0; ks < 2; ++ks) {
            short8 pf[2];
#pragma unroll
            for (int mt = 0; mt < 2; ++mt) {
                pf[mt] = *(const short8*)&Ps[w * 32 + mt * 16 + lane15][ks * 32 + quad * 8];
                lacc[mt] = __builtin_amdgcn_mfma_f32_16x16x32_bf16(pf[mt], ones, lacc[mt], 0, 0, 0);
            }
#pragma unroll
            for (int t2 = 0; t2 < 4; ++t2) {
                short8 vf = *(const short8*)&vsb[((t2 * 16 + lane15) << 6) +
                                                 ((((ks << 2) + quad) ^ (lane15 & 7)) << 3)];
                o[0][t2] = __builtin_amdgcn_mfma_f32_16x16x32_bf16(pf[0], vf, o[0][t2], 0, 0, 0);
                o[1][t2] = __builtin_amdgcn_mfma_f32_16x16x32_bf16(pf[1], vf, o[1][t2], 0, 0, 0);
            }
        }
        __syncthreads();
        cur = nxt;
    }

#pragma unroll
    for (int mt = 0; mt < 2; ++mt) {
        float inv[4];
#pragma unroll
        for (int r = 0; r < 4; ++r) inv[r] = 1.0f / lacc[mt][r];
#pragma unroll
        for (int t2 = 0; t2 < 4; ++t2)
#pragma unroll
            for (int r = 0; r < 4; ++r) {
                int q = qt * 128 + w * 32 + mt * 16 + quad * 4 + r;
                int col = h * EH + t2 * 16 + lane15;
                ctx[((size_t)(b * SEQ + q)) * DM + col] = f2bf(o[mt][t2][r] * inv[r]);
            }
    }
}

extern "C" void kernel_launch(void* const* d_in, const int* in_sizes, int n_in,
                              void* d_out, int out_size, void* d_ws, size_t ws_size,
                              hipStream_t stream)
{
    const float* queries = (const float*)d_in[0];
    const float* keys    = (const float*)d_in[1];
    const float* values  = (const float*)d_in[2];
    const float* Wq = (const float*)d_in[3];
    const float* bq = (const float*)d_in[4];
    const float* Wk = (const float*)d_in[5];
    const float* bk = (const float*)d_in[6];
    const float* Wv = (const float*)d_in[7];
    const float* bv = (const float*)d_in[8];
    const float* Wo = (const float*)d_in[9];
    const float* bo = (const float*)d_in[10];
    float* out = (float*)d_out;

    // 32 MB workspace (ushort elems):
    //   [0,4M)   Qh    (WoT overlays after attn)
    //   [4M,8M)  Kh
    //   [8M,12M) Vt
    //   [12M,16M) ctx  (WqT/WkT/WvT live here until attn overwrites)
    unsigned short* ws = (unsigned short*)d_ws;
    const size_t MAT = (size_t)MROWS * DM;   // 4M elems
    const size_t WSZ = (size_t)DM * DM;      // 1M elems
    unsigned short* Qhp = ws;
    unsigned short* Khp = ws + MAT;
    unsigned short* Vtp = ws + 2 * MAT;
    unsigned short* ctx = ws + 3 * MAT;
    unsigned short* WqT = ctx;               // dead once attn writes ctx
    unsigned short* WkT = ctx + WSZ;
    unsigned short* WvT = ctx + 2 * WSZ;
    unsigned short* WoT = ws;                // overlays Qh after attn

    // 1/sqrt(EH) * log2(e): exp2(S') == exp(S/8)
    const float qscale = 0.125f * 1.44269504088896f;

    // 1. weight transposes Wq/Wk/Wv
    transpose_w<<<dim3(DM / 32, DM / 32, 3), 256, 0, stream>>>(
        Wq, Wk, Wv, Wo, WqT, WkT, WvT, WoT, 0);

    // 2. fused Q/K/V projections (XCD-pinned swizzle + reg-prefetch pipeline)
    ProjArgs pa;
    pa.act[0] = queries; pa.act[1] = keys; pa.act[2] = values;
    pa.wt[0] = WqT;      pa.wt[1] = WkT;   pa.wt[2] = WvT;
    pa.bias[0] = bq;     pa.bias[1] = bk;  pa.bias[2] = bv;
    pa.C[0] = Qhp;       pa.C[1] = Khp;    pa.C[2] = Vtp;
    pa.oscale[0] = qscale; pa.oscale[1] = 1.f; pa.oscale[2] = 1.f;
    proj_qkv<<<dim3(8, 32, 3), 256, 0, stream>>>(pa);

    // 3. attention -> ctx (clobbers WqT/WkT/WvT, dead)
    attn_mfma<<<dim3(SEQ / 128, NH, BATCH), 256, 0, stream>>>(Qhp, Khp, Vtp, ctx);

    // 4. Wo transpose into dead Qh region
    transpose_w<<<dim3(DM / 32, DM / 32, 1), 256, 0, stream>>>(
        Wq, Wk, Wv, Wo, WqT, WkT, WvT, WoT, 3);

    // 5. output projection (XCD-pinned swizzle)
    gemm_out<<<dim3(16, 32), 256, 0, stream>>>(ctx, WoT, bo, out);
}